// Round 2
// baseline (1076.931 us; speedup 1.0000x reference)
//
#include <hip/hip_runtime.h>
#include <math.h>

#define EPS 1e-6f

// ---------------------------------------------------------------------------
// Fused entity GEMM: Pt[r][c] = emb_ent[r] . attn_W[c, 0:64]
//                    PQh[r][c] = { emb_ent[r].attn_W[c,64:128] + attn_b[c],
//                                  emb_ent[r].aggr_W[c, 0:64]  + aggr_b[c] }
// One A-tile stage, three W slices against it.
// ---------------------------------------------------------------------------
__global__ __launch_bounds__(256) void gemm_ent(
    const float* __restrict__ A, int M,
    const float* __restrict__ attn_W,   // [64 x 192]
    const float* __restrict__ aggr_W,   // [64 x 128]
    const float* __restrict__ attn_b, const float* __restrict__ aggr_b,
    float* __restrict__ Pt, float2* __restrict__ PQh)
{
    __shared__ float As[64][68];
    __shared__ float Ws[64][68];
    const int tid = threadIdx.x;
    const int r0 = blockIdx.x * 64;

    for (int t = tid; t < 1024; t += 256) {
        int r = t >> 4, c4 = (t & 15) << 2;
        float4 v = make_float4(0.f, 0.f, 0.f, 0.f);
        if (r0 + r < M)
            v = *reinterpret_cast<const float4*>(A + (size_t)(r0 + r) * 64 + c4);
        *reinterpret_cast<float4*>(&As[r][c4]) = v;
    }

    const int ti = tid >> 4;   // 0..15
    const int tj = tid & 15;   // 0..15
    float acc[3][4][4];

    const float* Wsrc[3] = { attn_W, attn_W + 64, aggr_W };
    const int    Wld[3]  = { 192, 192, 128 };

#pragma unroll
    for (int s = 0; s < 3; ++s) {
        __syncthreads();   // As ready (s=0) / previous compute done (s>0)
        for (int t = tid; t < 1024; t += 256) {
            int d = t >> 4, c4 = (t & 15) << 2;
            *reinterpret_cast<float4*>(&Ws[d][c4]) =
                *reinterpret_cast<const float4*>(Wsrc[s] + (size_t)d * Wld[s] + c4);
        }
        __syncthreads();

#pragma unroll
        for (int i = 0; i < 4; ++i)
#pragma unroll
            for (int j = 0; j < 4; ++j) acc[s][i][j] = 0.f;

#pragma unroll
        for (int k = 0; k < 64; k += 4) {
            float4 a4[4], w4[4];
#pragma unroll
            for (int i = 0; i < 4; ++i)
                a4[i] = *reinterpret_cast<const float4*>(&As[ti + 16 * i][k]);
#pragma unroll
            for (int j = 0; j < 4; ++j)
                w4[j] = *reinterpret_cast<const float4*>(&Ws[tj + 16 * j][k]);
#pragma unroll
            for (int i = 0; i < 4; ++i)
#pragma unroll
                for (int j = 0; j < 4; ++j) {
                    acc[s][i][j] += a4[i].x * w4[j].x;
                    acc[s][i][j] += a4[i].y * w4[j].y;
                    acc[s][i][j] += a4[i].z * w4[j].z;
                    acc[s][i][j] += a4[i].w * w4[j].w;
                }
        }
    }

#pragma unroll
    for (int i = 0; i < 4; ++i) {
        int r = r0 + ti + 16 * i;
        if (r < M) {
#pragma unroll
            for (int j = 0; j < 4; ++j) {
                int c = tj + 16 * j;
                Pt[(size_t)r * 64 + c] = acc[0][i][j];
                PQh[(size_t)r * 64 + c] =
                    make_float2(acc[1][i][j] + attn_b[c], acc[2][i][j] + aggr_b[c]);
            }
        }
    }
}

// ---------------------------------------------------------------------------
// Fused relation GEMM: PQr[r][c] = { emb_rel[r].attn_W[c,128:192],
//                                    emb_rel[r].aggr_W[c, 64:128] }
// ---------------------------------------------------------------------------
__global__ __launch_bounds__(256) void gemm_rel(
    const float* __restrict__ A, int M,
    const float* __restrict__ attn_W,
    const float* __restrict__ aggr_W,
    float2* __restrict__ PQr)
{
    __shared__ float As[64][68];
    __shared__ float Ws[64][68];
    const int tid = threadIdx.x;
    const int r0 = blockIdx.x * 64;

    for (int t = tid; t < 1024; t += 256) {
        int r = t >> 4, c4 = (t & 15) << 2;
        float4 v = make_float4(0.f, 0.f, 0.f, 0.f);
        if (r0 + r < M)
            v = *reinterpret_cast<const float4*>(A + (size_t)(r0 + r) * 64 + c4);
        *reinterpret_cast<float4*>(&As[r][c4]) = v;
    }

    const int ti = tid >> 4, tj = tid & 15;
    float acc[2][4][4];
    const float* Wsrc[2] = { attn_W + 128, aggr_W + 64 };
    const int    Wld[2]  = { 192, 128 };

#pragma unroll
    for (int s = 0; s < 2; ++s) {
        __syncthreads();
        for (int t = tid; t < 1024; t += 256) {
            int d = t >> 4, c4 = (t & 15) << 2;
            *reinterpret_cast<float4*>(&Ws[d][c4]) =
                *reinterpret_cast<const float4*>(Wsrc[s] + (size_t)d * Wld[s] + c4);
        }
        __syncthreads();
#pragma unroll
        for (int i = 0; i < 4; ++i)
#pragma unroll
            for (int j = 0; j < 4; ++j) acc[s][i][j] = 0.f;
#pragma unroll
        for (int k = 0; k < 64; k += 4) {
            float4 a4[4], w4[4];
#pragma unroll
            for (int i = 0; i < 4; ++i)
                a4[i] = *reinterpret_cast<const float4*>(&As[ti + 16 * i][k]);
#pragma unroll
            for (int j = 0; j < 4; ++j)
                w4[j] = *reinterpret_cast<const float4*>(&Ws[tj + 16 * j][k]);
#pragma unroll
            for (int i = 0; i < 4; ++i)
#pragma unroll
                for (int j = 0; j < 4; ++j) {
                    acc[s][i][j] += a4[i].x * w4[j].x;
                    acc[s][i][j] += a4[i].y * w4[j].y;
                    acc[s][i][j] += a4[i].z * w4[j].z;
                    acc[s][i][j] += a4[i].w * w4[j].w;
                }
        }
    }

#pragma unroll
    for (int i = 0; i < 4; ++i) {
        int r = r0 + ti + 16 * i;
        if (r < M) {
#pragma unroll
            for (int j = 0; j < 4; ++j) {
                int c = tj + 16 * j;
                PQr[(size_t)r * 64 + c] = make_float2(acc[0][i][j], acc[1][i][j]);
            }
        }
    }
}

// ---------------------------------------------------------------------------
// CSR build: histogram, scan, placement
// ---------------------------------------------------------------------------
__global__ __launch_bounds__(256) void hist_kernel(const int* __restrict__ tail, int E,
                                                   int* __restrict__ deg)
{
    int e = blockIdx.x * 256 + threadIdx.x;
    if (e < E) atomicAdd(&deg[tail[e]], 1);
}

__global__ __launch_bounds__(256) void scan_chunk(const int* __restrict__ deg, int n,
                                                  int* __restrict__ incl, int* __restrict__ bsums)
{
    __shared__ int s[256];
    int tid = threadIdx.x;
    int i = blockIdx.x * 256 + tid;
    int v = (i < n) ? deg[i] : 0;
    int acc = v;
    s[tid] = acc;
    __syncthreads();
#pragma unroll
    for (int off = 1; off < 256; off <<= 1) {
        int add = (tid >= off) ? s[tid - off] : 0;
        __syncthreads();
        acc += add;
        s[tid] = acc;
        __syncthreads();
    }
    if (i < n) incl[i] = acc;
    if (tid == 255) bsums[blockIdx.x] = acc;
}

__global__ __launch_bounds__(256) void scan_tops(int* __restrict__ bsums, int nb)
{
    __shared__ int s[256];
    int tid = threadIdx.x;
    int v = (tid < nb) ? bsums[tid] : 0;
    int acc = v;
    s[tid] = acc;
    __syncthreads();
#pragma unroll
    for (int off = 1; off < 256; off <<= 1) {
        int add = (tid >= off) ? s[tid - off] : 0;
        __syncthreads();
        acc += add;
        s[tid] = acc;
        __syncthreads();
    }
    if (tid < nb) bsums[tid] = acc - v;
}

__global__ __launch_bounds__(256) void scan_final(const int* __restrict__ deg,
                                                  const int* __restrict__ incl,
                                                  const int* __restrict__ bsums, int n,
                                                  int* __restrict__ off, int* __restrict__ cursor)
{
    int i = blockIdx.x * 256 + threadIdx.x;
    if (i < n) {
        int e = incl[i] - deg[i] + bsums[blockIdx.x];
        off[i] = e;
        cursor[i] = e;
    }
}

__global__ __launch_bounds__(256) void place_kernel(const int* __restrict__ head,
                                                    const int* __restrict__ tail,
                                                    const int* __restrict__ rel, int E,
                                                    int* __restrict__ cursor,
                                                    unsigned int* __restrict__ shr)
{
    int e = blockIdx.x * 256 + threadIdx.x;
    if (e < E) {
        int t = tail[e];
        int p = atomicAdd(&cursor[t], 1);
        shr[p] = ((unsigned int)head[e] << 8) | (unsigned int)rel[e];
    }
}

// ---------------------------------------------------------------------------
// Main: one wave per node, lane = output dim. No-max softmax (logits are O(1)
// by construction, shift-invariance makes it exact up to fp error), float2
// interleaved gathers, biases pre-folded into tables, 2-deep pipeline.
// ---------------------------------------------------------------------------
__global__ __launch_bounds__(256) void ingram_main(
    const float* __restrict__ Pt,
    const float2* __restrict__ PQh,      // {Ph+attn_b, Qh+aggr_b}
    const float2* __restrict__ PQr,      // {Pr, Qr}
    const int* __restrict__ deg, const int* __restrict__ off,
    const unsigned int* __restrict__ shr,
    const float* __restrict__ attn_vec,
    float* __restrict__ out, int N)
{
    const int lane = threadIdx.x & 63;
    const int node = blockIdx.x * 4 + (threadIdx.x >> 6);
    if (node >= N) return;

    const float vec = attn_vec[lane];
    const float ptd = Pt[(size_t)node * 64 + lane];
    const char* HB = (const char*)PQh;
    const char* RB = (const char*)PQr;
    const unsigned laneoff = (unsigned)lane << 3;

    const int start = off[node];
    const int dg    = deg[node];

    float S = 0.f, O = 0.f, SP = 0.f, SQ = 0.f;

    for (int cstart = 0; cstart < dg; cstart += 64) {
        const int nc = min(64, dg - cstart);
        unsigned pk = 0u;
        if (lane < nc) pk = shr[start + cstart + lane];

        unsigned p0 = (unsigned)__shfl((int)pk, 0);
        float2 h0 = *(const float2*)(HB + (((p0 >> 8) << 9) | laneoff));
        float2 r0 = *(const float2*)(RB + (((p0 & 255u) << 9) | laneoff));
        float2 h1 = h0, r1 = r0;
        if (nc > 1) {
            unsigned p1 = (unsigned)__shfl((int)pk, 1);
            h1 = *(const float2*)(HB + (((p1 >> 8) << 9) | laneoff));
            r1 = *(const float2*)(RB + (((p1 & 255u) << 9) | laneoff));
        }

        for (int j = 0; j < nc; ++j) {
            float2 hc = h0, rc = r0;
            h0 = h1; r0 = r1;
            if (j + 2 < nc) {
                unsigned pn = (unsigned)__shfl((int)pk, j + 2);
                h1 = *(const float2*)(HB + (((pn >> 8) << 9) | laneoff));
                r1 = *(const float2*)(RB + (((pn & 255u) << 9) | laneoff));
            }
            SP += rc.x;
            SQ += rc.y;
            float pre = ptd + hc.x + rc.x;
            float a   = fmaxf(pre, 0.2f * pre);    // leaky_relu(0.2)
            float t   = a * vec;
            t += __shfl_xor(t, 1);
            t += __shfl_xor(t, 2);
            t += __shfl_xor(t, 4);
            float av = __expf(t);
            S += av;
            O = fmaf(av, hc.y + rc.y, O);
        }
    }

    // self-loop: rel features = (sum of incoming Pr/Qr)/(deg+eps); biases
    // already inside PQh.
    {
        const float inv = 1.f / ((float)dg + EPS);
        float2 hs = *(const float2*)(HB + (((unsigned)node << 9) | laneoff));
        float pre = ptd + hs.x + SP * inv;
        float a   = fmaxf(pre, 0.2f * pre);
        float t   = a * vec;
        t += __shfl_xor(t, 1);
        t += __shfl_xor(t, 2);
        t += __shfl_xor(t, 4);
        float av = __expf(t);
        S += av;
        O = fmaf(av, hs.y + SQ * inv, O);
    }

    out[(size_t)node * 64 + lane] = O / (S + EPS);
}

// ---------------------------------------------------------------------------
extern "C" void kernel_launch(void* const* d_in, const int* in_sizes, int n_in,
                              void* d_out, int out_size, void* d_ws, size_t ws_size,
                              hipStream_t stream)
{
    const float* emb_ent  = (const float*)d_in[0];
    const float* emb_rel  = (const float*)d_in[1];
    const float* attn_W   = (const float*)d_in[2];   // [64 x 192]
    const float* attn_b   = (const float*)d_in[3];
    const float* attn_vec = (const float*)d_in[4];   // 64
    const float* aggr_W   = (const float*)d_in[5];   // [64 x 128]
    const float* aggr_b   = (const float*)d_in[6];
    const int*   head     = (const int*)d_in[7];
    const int*   tail     = (const int*)d_in[8];
    const int*   rel      = (const int*)d_in[9];

    const int N = in_sizes[0] / 64;
    const int R = in_sizes[1] / 64;
    const int E = in_sizes[7];

    char* w = (char*)d_ws;
    float*  Pt  = (float*)w;          w += (size_t)N * 64 * sizeof(float);
    float2* PQh = (float2*)w;         w += (size_t)N * 64 * sizeof(float2);
    float2* PQr = (float2*)w;         w += (size_t)R * 64 * sizeof(float2);
    int* deg    = (int*)w;            w += (size_t)N * sizeof(int);
    int* incl   = (int*)w;            w += (size_t)N * sizeof(int);
    int* offs   = (int*)w;            w += (size_t)N * sizeof(int);
    int* cursor = (int*)w;            w += (size_t)N * sizeof(int);
    int* bsums  = (int*)w;            w += 256 * sizeof(int);
    unsigned int* shr = (unsigned int*)w;  w += (size_t)E * sizeof(unsigned int);

    // CSR by tail
    hipMemsetAsync(deg, 0, (size_t)N * sizeof(int), stream);
    hist_kernel<<<(E + 255) / 256, 256, 0, stream>>>(tail, E, deg);
    int nb = (N + 255) / 256;
    scan_chunk<<<nb, 256, 0, stream>>>(deg, N, incl, bsums);
    scan_tops<<<1, 256, 0, stream>>>(bsums, nb);
    scan_final<<<nb, 256, 0, stream>>>(deg, incl, bsums, N, offs, cursor);
    place_kernel<<<(E + 255) / 256, 256, 0, stream>>>(head, tail, rel, E, cursor, shr);

    // projection tables (fused)
    gemm_ent<<<(N + 63) / 64, 256, 0, stream>>>(emb_ent, N, attn_W, aggr_W,
                                                attn_b, aggr_b, Pt, PQh);
    gemm_rel<<<(R + 63) / 64, 256, 0, stream>>>(emb_rel, R, attn_W, aggr_W, PQr);

    // per-node aggregation
    ingram_main<<<(N + 3) / 4, 256, 0, stream>>>(Pt, PQh, PQr, deg, offs, shr,
                                                 attn_vec, (float*)d_out, N);
}

// Round 3
// 272.091 us; speedup vs baseline: 3.9580x; 3.9580x over previous
//
#include <hip/hip_runtime.h>
#include <math.h>

#define EPS 1e-6f

// ---------------------------------------------------------------------------
// One 64x64 GEMM slice: stages W slice into LDS, computes acc = As . Ws^T.
// All arguments are compile-time distinct at each call site; acc is a fresh
// local array per call => no runtime-indexed register arrays (no scratch).
// ---------------------------------------------------------------------------
__device__ __forceinline__ void slice_compute(
    const float (*As)[68], float (*Ws)[68],
    const float* __restrict__ Wsrc, int ldw,
    int tid, int ti, int tj, float acc[4][4])
{
    __syncthreads();   // previous users of Ws / As staging done
    for (int t = tid; t < 1024; t += 256) {
        int d = t >> 4, c4 = (t & 15) << 2;
        *reinterpret_cast<float4*>(&Ws[d][c4]) =
            *reinterpret_cast<const float4*>(Wsrc + (size_t)d * ldw + c4);
    }
    __syncthreads();

#pragma unroll
    for (int i = 0; i < 4; ++i)
#pragma unroll
        for (int j = 0; j < 4; ++j) acc[i][j] = 0.f;

#pragma unroll
    for (int k = 0; k < 64; k += 4) {
        float4 a4[4], w4[4];
#pragma unroll
        for (int i = 0; i < 4; ++i)
            a4[i] = *reinterpret_cast<const float4*>(&As[ti + 16 * i][k]);
#pragma unroll
        for (int j = 0; j < 4; ++j)
            w4[j] = *reinterpret_cast<const float4*>(&Ws[tj + 16 * j][k]);
#pragma unroll
        for (int i = 0; i < 4; ++i)
#pragma unroll
            for (int j = 0; j < 4; ++j) {
                acc[i][j] += a4[i].x * w4[j].x;
                acc[i][j] += a4[i].y * w4[j].y;
                acc[i][j] += a4[i].z * w4[j].z;
                acc[i][j] += a4[i].w * w4[j].w;
            }
    }
}

// ---------------------------------------------------------------------------
// Fused entity GEMM: Pt = emb_ent . attn_W[:,0:64]^T
//                    PQh = { emb_ent.attn_W[:,64:128]^T + attn_b,
//                            emb_ent.aggr_W[:, 0:64 ]^T + aggr_b }   (float2)
// A-tile staged once; three static slices, each stored before the next.
// ---------------------------------------------------------------------------
__global__ __launch_bounds__(256) void gemm_ent(
    const float* __restrict__ A, int M,
    const float* __restrict__ attn_W,   // [64 x 192]
    const float* __restrict__ aggr_W,   // [64 x 128]
    const float* __restrict__ attn_b, const float* __restrict__ aggr_b,
    float* __restrict__ Pt, float* __restrict__ PQh)  // PQh as float* (interleaved x2)
{
    __shared__ float As[64][68];
    __shared__ float Ws[64][68];
    const int tid = threadIdx.x;
    const int r0 = blockIdx.x * 64;
    const int ti = tid >> 4, tj = tid & 15;

    for (int t = tid; t < 1024; t += 256) {
        int r = t >> 4, c4 = (t & 15) << 2;
        float4 v = make_float4(0.f, 0.f, 0.f, 0.f);
        if (r0 + r < M)
            v = *reinterpret_cast<const float4*>(A + (size_t)(r0 + r) * 64 + c4);
        *reinterpret_cast<float4*>(&As[r][c4]) = v;
    }

    // slice 0: Pt
    {
        float acc[4][4];
        slice_compute(As, Ws, attn_W, 192, tid, ti, tj, acc);
#pragma unroll
        for (int i = 0; i < 4; ++i) {
            int r = r0 + ti + 16 * i;
            if (r < M)
#pragma unroll
                for (int j = 0; j < 4; ++j)
                    Pt[(size_t)r * 64 + tj + 16 * j] = acc[i][j];
        }
    }
    // slice 1: PQh.x = Ph + attn_b
    {
        float acc[4][4];
        slice_compute(As, Ws, attn_W + 64, 192, tid, ti, tj, acc);
#pragma unroll
        for (int i = 0; i < 4; ++i) {
            int r = r0 + ti + 16 * i;
            if (r < M)
#pragma unroll
                for (int j = 0; j < 4; ++j) {
                    int c = tj + 16 * j;
                    PQh[((size_t)r * 64 + c) * 2 + 0] = acc[i][j] + attn_b[c];
                }
        }
    }
    // slice 2: PQh.y = Qh + aggr_b
    {
        float acc[4][4];
        slice_compute(As, Ws, aggr_W, 128, tid, ti, tj, acc);
#pragma unroll
        for (int i = 0; i < 4; ++i) {
            int r = r0 + ti + 16 * i;
            if (r < M)
#pragma unroll
                for (int j = 0; j < 4; ++j) {
                    int c = tj + 16 * j;
                    PQh[((size_t)r * 64 + c) * 2 + 1] = acc[i][j] + aggr_b[c];
                }
        }
    }
}

// ---------------------------------------------------------------------------
// Fused relation GEMM: PQr = { emb_rel.attn_W[:,128:192]^T,
//                              emb_rel.aggr_W[:, 64:128]^T }   (float2)
// ---------------------------------------------------------------------------
__global__ __launch_bounds__(256) void gemm_rel(
    const float* __restrict__ A, int M,
    const float* __restrict__ attn_W,
    const float* __restrict__ aggr_W,
    float* __restrict__ PQr)
{
    __shared__ float As[64][68];
    __shared__ float Ws[64][68];
    const int tid = threadIdx.x;
    const int r0 = blockIdx.x * 64;
    const int ti = tid >> 4, tj = tid & 15;

    for (int t = tid; t < 1024; t += 256) {
        int r = t >> 4, c4 = (t & 15) << 2;
        float4 v = make_float4(0.f, 0.f, 0.f, 0.f);
        if (r0 + r < M)
            v = *reinterpret_cast<const float4*>(A + (size_t)(r0 + r) * 64 + c4);
        *reinterpret_cast<float4*>(&As[r][c4]) = v;
    }

    // slice 0: PQr.x = Pr
    {
        float acc[4][4];
        slice_compute(As, Ws, attn_W + 128, 192, tid, ti, tj, acc);
#pragma unroll
        for (int i = 0; i < 4; ++i) {
            int r = r0 + ti + 16 * i;
            if (r < M)
#pragma unroll
                for (int j = 0; j < 4; ++j)
                    PQr[((size_t)r * 64 + tj + 16 * j) * 2 + 0] = acc[i][j];
        }
    }
    // slice 1: PQr.y = Qr
    {
        float acc[4][4];
        slice_compute(As, Ws, aggr_W + 64, 128, tid, ti, tj, acc);
#pragma unroll
        for (int i = 0; i < 4; ++i) {
            int r = r0 + ti + 16 * i;
            if (r < M)
#pragma unroll
                for (int j = 0; j < 4; ++j)
                    PQr[((size_t)r * 64 + tj + 16 * j) * 2 + 1] = acc[i][j];
        }
    }
}

// ---------------------------------------------------------------------------
// CSR build: histogram, scan, placement
// ---------------------------------------------------------------------------
__global__ __launch_bounds__(256) void hist_kernel(const int* __restrict__ tail, int E,
                                                   int* __restrict__ deg)
{
    int e = blockIdx.x * 256 + threadIdx.x;
    if (e < E) atomicAdd(&deg[tail[e]], 1);
}

__global__ __launch_bounds__(256) void scan_chunk(const int* __restrict__ deg, int n,
                                                  int* __restrict__ incl, int* __restrict__ bsums)
{
    __shared__ int s[256];
    int tid = threadIdx.x;
    int i = blockIdx.x * 256 + tid;
    int v = (i < n) ? deg[i] : 0;
    int acc = v;
    s[tid] = acc;
    __syncthreads();
#pragma unroll
    for (int off = 1; off < 256; off <<= 1) {
        int add = (tid >= off) ? s[tid - off] : 0;
        __syncthreads();
        acc += add;
        s[tid] = acc;
        __syncthreads();
    }
    if (i < n) incl[i] = acc;
    if (tid == 255) bsums[blockIdx.x] = acc;
}

__global__ __launch_bounds__(256) void scan_tops(int* __restrict__ bsums, int nb)
{
    __shared__ int s[256];
    int tid = threadIdx.x;
    int v = (tid < nb) ? bsums[tid] : 0;
    int acc = v;
    s[tid] = acc;
    __syncthreads();
#pragma unroll
    for (int off = 1; off < 256; off <<= 1) {
        int add = (tid >= off) ? s[tid - off] : 0;
        __syncthreads();
        acc += add;
        s[tid] = acc;
        __syncthreads();
    }
    if (tid < nb) bsums[tid] = acc - v;
}

__global__ __launch_bounds__(256) void scan_final(const int* __restrict__ deg,
                                                  const int* __restrict__ incl,
                                                  const int* __restrict__ bsums, int n,
                                                  int* __restrict__ off, int* __restrict__ cursor)
{
    int i = blockIdx.x * 256 + threadIdx.x;
    if (i < n) {
        int e = incl[i] - deg[i] + bsums[blockIdx.x];
        off[i] = e;
        cursor[i] = e;
    }
}

__global__ __launch_bounds__(256) void place_kernel(const int* __restrict__ head,
                                                    const int* __restrict__ tail,
                                                    const int* __restrict__ rel, int E,
                                                    int* __restrict__ cursor,
                                                    unsigned int* __restrict__ shr)
{
    int e = blockIdx.x * 256 + threadIdx.x;
    if (e < E) {
        int t = tail[e];
        int p = atomicAdd(&cursor[t], 1);
        shr[p] = ((unsigned int)head[e] << 8) | (unsigned int)rel[e];
    }
}

// ---------------------------------------------------------------------------
// Main: one wave per node, lane = output dim. No-max softmax (logits are O(1),
// shift-invariance), float2 interleaved gathers, biases pre-folded, 2-deep
// software pipeline.
// ---------------------------------------------------------------------------
__global__ __launch_bounds__(256) void ingram_main(
    const float* __restrict__ Pt,
    const float2* __restrict__ PQh,      // {Ph+attn_b, Qh+aggr_b}
    const float2* __restrict__ PQr,      // {Pr, Qr}
    const int* __restrict__ deg, const int* __restrict__ off,
    const unsigned int* __restrict__ shr,
    const float* __restrict__ attn_vec,
    float* __restrict__ out, int N)
{
    const int lane = threadIdx.x & 63;
    const int node = blockIdx.x * 4 + (threadIdx.x >> 6);
    if (node >= N) return;

    const float vec = attn_vec[lane];
    const float ptd = Pt[(size_t)node * 64 + lane];
    const char* HB = (const char*)PQh;
    const char* RB = (const char*)PQr;
    const unsigned laneoff = (unsigned)lane << 3;

    const int start = off[node];
    const int dg    = deg[node];

    float S = 0.f, O = 0.f, SP = 0.f, SQ = 0.f;

    for (int cstart = 0; cstart < dg; cstart += 64) {
        const int nc = min(64, dg - cstart);
        unsigned pk = 0u;
        if (lane < nc) pk = shr[start + cstart + lane];

        unsigned p0 = (unsigned)__shfl((int)pk, 0);
        float2 h0 = *(const float2*)(HB + (((p0 >> 8) << 9) | laneoff));
        float2 r0 = *(const float2*)(RB + (((p0 & 255u) << 9) | laneoff));
        float2 h1 = h0, r1 = r0;
        if (nc > 1) {
            unsigned p1 = (unsigned)__shfl((int)pk, 1);
            h1 = *(const float2*)(HB + (((p1 >> 8) << 9) | laneoff));
            r1 = *(const float2*)(RB + (((p1 & 255u) << 9) | laneoff));
        }

        for (int j = 0; j < nc; ++j) {
            float2 hc = h0, rc = r0;
            h0 = h1; r0 = r1;
            if (j + 2 < nc) {
                unsigned pn = (unsigned)__shfl((int)pk, j + 2);
                h1 = *(const float2*)(HB + (((pn >> 8) << 9) | laneoff));
                r1 = *(const float2*)(RB + (((pn & 255u) << 9) | laneoff));
            }
            SP += rc.x;
            SQ += rc.y;
            float pre = ptd + hc.x + rc.x;
            float a   = fmaxf(pre, 0.2f * pre);    // leaky_relu(0.2)
            float t   = a * vec;
            t += __shfl_xor(t, 1);
            t += __shfl_xor(t, 2);
            t += __shfl_xor(t, 4);
            float av = __expf(t);
            S += av;
            O = fmaf(av, hc.y + rc.y, O);
        }
    }

    // self-loop: rel features = (sum of incoming Pr/Qr)/(deg+eps); biases
    // already folded into PQh.
    {
        const float inv = 1.f / ((float)dg + EPS);
        float2 hs = *(const float2*)(HB + (((unsigned)node << 9) | laneoff));
        float pre = ptd + hs.x + SP * inv;
        float a   = fmaxf(pre, 0.2f * pre);
        float t   = a * vec;
        t += __shfl_xor(t, 1);
        t += __shfl_xor(t, 2);
        t += __shfl_xor(t, 4);
        float av = __expf(t);
        S += av;
        O = fmaf(av, hs.y + SQ * inv, O);
    }

    out[(size_t)node * 64 + lane] = O / (S + EPS);
}

// ---------------------------------------------------------------------------
extern "C" void kernel_launch(void* const* d_in, const int* in_sizes, int n_in,
                              void* d_out, int out_size, void* d_ws, size_t ws_size,
                              hipStream_t stream)
{
    const float* emb_ent  = (const float*)d_in[0];
    const float* emb_rel  = (const float*)d_in[1];
    const float* attn_W   = (const float*)d_in[2];   // [64 x 192]
    const float* attn_b   = (const float*)d_in[3];
    const float* attn_vec = (const float*)d_in[4];   // 64
    const float* aggr_W   = (const float*)d_in[5];   // [64 x 128]
    const float* aggr_b   = (const float*)d_in[6];
    const int*   head     = (const int*)d_in[7];
    const int*   tail     = (const int*)d_in[8];
    const int*   rel      = (const int*)d_in[9];

    const int N = in_sizes[0] / 64;
    const int R = in_sizes[1] / 64;
    const int E = in_sizes[7];

    char* w = (char*)d_ws;
    float*  Pt  = (float*)w;          w += (size_t)N * 64 * sizeof(float);
    float2* PQh = (float2*)w;         w += (size_t)N * 64 * sizeof(float2);
    float2* PQr = (float2*)w;         w += (size_t)R * 64 * sizeof(float2);
    int* deg    = (int*)w;            w += (size_t)N * sizeof(int);
    int* incl   = (int*)w;            w += (size_t)N * sizeof(int);
    int* offs   = (int*)w;            w += (size_t)N * sizeof(int);
    int* cursor = (int*)w;            w += (size_t)N * sizeof(int);
    int* bsums  = (int*)w;            w += 256 * sizeof(int);
    unsigned int* shr = (unsigned int*)w;  w += (size_t)E * sizeof(unsigned int);

    // CSR by tail
    hipMemsetAsync(deg, 0, (size_t)N * sizeof(int), stream);
    hist_kernel<<<(E + 255) / 256, 256, 0, stream>>>(tail, E, deg);
    int nb = (N + 255) / 256;
    scan_chunk<<<nb, 256, 0, stream>>>(deg, N, incl, bsums);
    scan_tops<<<1, 256, 0, stream>>>(bsums, nb);
    scan_final<<<nb, 256, 0, stream>>>(deg, incl, bsums, N, offs, cursor);
    place_kernel<<<(E + 255) / 256, 256, 0, stream>>>(head, tail, rel, E, cursor, shr);

    // projection tables (fused, static slices)
    gemm_ent<<<(N + 63) / 64, 256, 0, stream>>>(emb_ent, N, attn_W, aggr_W,
                                                attn_b, aggr_b, Pt, (float*)PQh);
    gemm_rel<<<(R + 63) / 64, 256, 0, stream>>>(emb_rel, R, attn_W, aggr_W,
                                                (float*)PQr);

    // per-node aggregation
    ingram_main<<<(N + 3) / 4, 256, 0, stream>>>(Pt, PQh, PQr, deg, offs, shr,
                                                 attn_vec, (float*)d_out, N);
}

// Round 4
// 256.246 us; speedup vs baseline: 4.2027x; 1.0618x over previous
//
#include <hip/hip_runtime.h>
#include <math.h>

#define EPS 1e-6f

__device__ __forceinline__ float4 f4fma(float s, float4 w, float4 acc) {
    acc.x = fmaf(s, w.x, acc.x);
    acc.y = fmaf(s, w.y, acc.y);
    acc.z = fmaf(s, w.z, acc.z);
    acc.w = fmaf(s, w.w, acc.w);
    return acc;
}

// 4-column dot: out[c..c+3] = sum_k a[k] * Ws[k][cb+ .. ]; 4-way split acc
// to break fma dependency chains. Ws reads are wave-uniform -> LDS broadcast.
template <int LDW>
__device__ __forceinline__ float4 dot4cols(const float (*Ws)[LDW],
                                           const float4* a4, int cb)
{
    float4 z = make_float4(0.f, 0.f, 0.f, 0.f);
    float4 acc0 = z, acc1 = z, acc2 = z, acc3 = z;
#pragma unroll
    for (int k4 = 0; k4 < 16; ++k4) {
        float4 av = a4[k4];
        float4 w0 = *reinterpret_cast<const float4*>(&Ws[4 * k4 + 0][cb]);
        float4 w1 = *reinterpret_cast<const float4*>(&Ws[4 * k4 + 1][cb]);
        float4 w2 = *reinterpret_cast<const float4*>(&Ws[4 * k4 + 2][cb]);
        float4 w3 = *reinterpret_cast<const float4*>(&Ws[4 * k4 + 3][cb]);
        acc0 = f4fma(av.x, w0, acc0);
        acc1 = f4fma(av.y, w1, acc1);
        acc2 = f4fma(av.z, w2, acc2);
        acc3 = f4fma(av.w, w3, acc3);
    }
    return make_float4((acc0.x + acc1.x) + (acc2.x + acc3.x),
                       (acc0.y + acc1.y) + (acc2.y + acc3.y),
                       (acc0.z + acc1.z) + (acc2.z + acc3.z),
                       (acc0.w + acc1.w) + (acc2.w + acc3.w));
}

// ---------------------------------------------------------------------------
// Entity tables: one thread per row. W' (192 cols x 64 k, transposed) in LDS.
//   cols   0..63  -> Pt            = A . attn_W[:,0:64]^T
//   cols  64..127 -> PQh[.x]       = A . attn_W[:,64:128]^T + attn_b
//   cols 128..191 -> PQh[.y]       = A . aggr_W[:,0:64]^T   + aggr_b
// ---------------------------------------------------------------------------
__global__ __launch_bounds__(256) void gemm_ent(
    const float* __restrict__ A, int M,
    const float* __restrict__ attn_W,   // [64 x 192]
    const float* __restrict__ aggr_W,   // [64 x 128]
    const float* __restrict__ attn_b, const float* __restrict__ aggr_b,
    float* __restrict__ Pt, float* __restrict__ PQh)
{
    __shared__ alignas(16) float Ws[64][196];   // stride 196 floats = 784 B (16B aligned)
    const int tid = threadIdx.x;

    for (int idx = tid; idx < 64 * 192; idx += 256) {
        int c = idx >> 6, k = idx & 63;
        float v;
        if (c < 64)       v = attn_W[c * 192 + k];
        else if (c < 128) v = attn_W[(c - 64) * 192 + 64 + k];
        else              v = aggr_W[(c - 128) * 128 + k];
        Ws[k][c] = v;
    }
    __syncthreads();

    const int r = blockIdx.x * 256 + tid;
    if (r >= M) return;

    float4 a4[16];
#pragma unroll
    for (int i = 0; i < 16; ++i)
        a4[i] = *reinterpret_cast<const float4*>(A + (size_t)r * 64 + i * 4);

    for (int cg = 0; cg < 16; ++cg) {
        float4 s = dot4cols<196>(Ws, a4, cg * 4);
        *reinterpret_cast<float4*>(Pt + (size_t)r * 64 + cg * 4) = s;
    }
    for (int cg = 0; cg < 16; ++cg) {
        float4 s = dot4cols<196>(Ws, a4, 64 + cg * 4);
        float4 bb = *reinterpret_cast<const float4*>(attn_b + cg * 4);
        float* dst = PQh + ((size_t)r * 64 + cg * 4) * 2;
        dst[0] = s.x + bb.x; dst[2] = s.y + bb.y;
        dst[4] = s.z + bb.z; dst[6] = s.w + bb.w;
    }
    for (int cg = 0; cg < 16; ++cg) {
        float4 s = dot4cols<196>(Ws, a4, 128 + cg * 4);
        float4 bb = *reinterpret_cast<const float4*>(aggr_b + cg * 4);
        float* dst = PQh + ((size_t)r * 64 + cg * 4) * 2;
        dst[1] = s.x + bb.x; dst[3] = s.y + bb.y;
        dst[5] = s.z + bb.z; dst[7] = s.w + bb.w;
    }
}

// ---------------------------------------------------------------------------
// Relation tables: 64 rows x 4 col-quarters per block.
//   cols  0..63  -> PQr[.x] = A . attn_W[:,128:192]^T
//   cols 64..127 -> PQr[.y] = A . aggr_W[:,64:128]^T
// ---------------------------------------------------------------------------
__global__ __launch_bounds__(256) void gemm_rel(
    const float* __restrict__ A, int Mr,
    const float* __restrict__ attn_W,
    const float* __restrict__ aggr_W,
    float* __restrict__ PQr)
{
    __shared__ alignas(16) float Ws[64][132];   // 528 B stride (16B aligned)
    const int tid = threadIdx.x;

    for (int idx = tid; idx < 64 * 128; idx += 256) {
        int c = idx >> 6, k = idx & 63;
        float v = (c < 64) ? attn_W[c * 192 + 128 + k]
                           : aggr_W[(c - 64) * 128 + 64 + k];
        Ws[k][c] = v;
    }
    __syncthreads();

    const int r = blockIdx.x * 64 + (tid & 63);
    const int q = tid >> 6;                 // col quarter 0..3
    if (r >= Mr) return;

    float4 a4[16];
#pragma unroll
    for (int i = 0; i < 16; ++i)
        a4[i] = *reinterpret_cast<const float4*>(A + (size_t)r * 64 + i * 4);

    for (int cg = 0; cg < 8; ++cg) {
        int cb = q * 32 + cg * 4;
        float4 s = dot4cols<132>(Ws, a4, cb);
#pragma unroll
        for (int i = 0; i < 4; ++i) {
            int c = cb + i;
            float v = (i == 0) ? s.x : (i == 1) ? s.y : (i == 2) ? s.z : s.w;
            if (c < 64) PQr[((size_t)r * 64 + c) * 2]            = v;
            else        PQr[((size_t)r * 64 + (c - 64)) * 2 + 1] = v;
        }
    }
}

// ---------------------------------------------------------------------------
// CSR build: histogram, scan, placement
// ---------------------------------------------------------------------------
__global__ __launch_bounds__(256) void hist_kernel(const int* __restrict__ tail, int E,
                                                   int* __restrict__ deg)
{
    int e = blockIdx.x * 256 + threadIdx.x;
    if (e < E) atomicAdd(&deg[tail[e]], 1);
}

__global__ __launch_bounds__(256) void scan_chunk(const int* __restrict__ deg, int n,
                                                  int* __restrict__ incl, int* __restrict__ bsums)
{
    __shared__ int s[256];
    int tid = threadIdx.x;
    int i = blockIdx.x * 256 + tid;
    int v = (i < n) ? deg[i] : 0;
    int acc = v;
    s[tid] = acc;
    __syncthreads();
#pragma unroll
    for (int off = 1; off < 256; off <<= 1) {
        int add = (tid >= off) ? s[tid - off] : 0;
        __syncthreads();
        acc += add;
        s[tid] = acc;
        __syncthreads();
    }
    if (i < n) incl[i] = acc;
    if (tid == 255) bsums[blockIdx.x] = acc;
}

__global__ __launch_bounds__(256) void scan_tops(int* __restrict__ bsums, int nb)
{
    __shared__ int s[256];
    int tid = threadIdx.x;
    int v = (tid < nb) ? bsums[tid] : 0;
    int acc = v;
    s[tid] = acc;
    __syncthreads();
#pragma unroll
    for (int off = 1; off < 256; off <<= 1) {
        int add = (tid >= off) ? s[tid - off] : 0;
        __syncthreads();
        acc += add;
        s[tid] = acc;
        __syncthreads();
    }
    if (tid < nb) bsums[tid] = acc - v;
}

__global__ __launch_bounds__(256) void scan_final(const int* __restrict__ deg,
                                                  const int* __restrict__ incl,
                                                  const int* __restrict__ bsums, int n,
                                                  int* __restrict__ off, int* __restrict__ cursor)
{
    int i = blockIdx.x * 256 + threadIdx.x;
    if (i < n) {
        int e = incl[i] - deg[i] + bsums[blockIdx.x];
        off[i] = e;
        cursor[i] = e;
    }
}

__global__ __launch_bounds__(256) void place_kernel(const int* __restrict__ head,
                                                    const int* __restrict__ tail,
                                                    const int* __restrict__ rel, int E,
                                                    int* __restrict__ cursor,
                                                    unsigned int* __restrict__ shr)
{
    int e = blockIdx.x * 256 + threadIdx.x;
    if (e < E) {
        int t = tail[e];
        int p = atomicAdd(&cursor[t], 1);
        shr[p] = ((unsigned int)head[e] << 8) | (unsigned int)rel[e];
    }
}

// ---------------------------------------------------------------------------
// Main: one wave per node, lane = output dim. Edge metadata fetched through
// SGPRs (wave-uniform): readfirstlane forces SALU unpack + SGPR-base gathers.
// No-max softmax (logits O(1), shift-invariance). Biases pre-folded.
// ---------------------------------------------------------------------------
__global__ __launch_bounds__(256) void ingram_main(
    const float* __restrict__ Pt,
    const float2* __restrict__ PQh,      // {Ph+attn_b, Qh+aggr_b}
    const float2* __restrict__ PQr,      // {Pr, Qr}
    const int* __restrict__ deg, const int* __restrict__ off,
    const unsigned int* __restrict__ shr,
    const float* __restrict__ attn_vec,
    float* __restrict__ out, int N)
{
    const int lane = threadIdx.x & 63;
    const int node = blockIdx.x * 4 + (threadIdx.x >> 6);
    if (node >= N) return;

    const float vec = attn_vec[lane];
    const float ptd = Pt[(size_t)node * 64 + lane];
    const char* HB = (const char*)PQh;
    const char* RB = (const char*)PQr;
    const unsigned laneoff = (unsigned)lane << 3;

    const int start = __builtin_amdgcn_readfirstlane(off[node]);
    const int dg    = __builtin_amdgcn_readfirstlane(deg[node]);

    float S = 0.f, O = 0.f, SP = 0.f, SQ = 0.f;

#pragma unroll 4
    for (int j = 0; j < dg; ++j) {
        unsigned p = __builtin_amdgcn_readfirstlane(shr[start + j]);
        const float2 h = *(const float2*)(HB + ((size_t)(p >> 8) << 9) + laneoff);
        const float2 r = *(const float2*)(RB + ((size_t)(p & 255u) << 9) + laneoff);
        SP += r.x;
        SQ += r.y;
        float pre = ptd + h.x + r.x;
        float a   = fmaxf(pre, 0.2f * pre);    // leaky_relu(0.2)
        float t   = a * vec;
        t += __shfl_xor(t, 1);
        t += __shfl_xor(t, 2);
        t += __shfl_xor(t, 4);
        float av = __expf(t);
        S += av;
        O = fmaf(av, h.y + r.y, O);
    }

    // self-loop: rel features = (sum of incoming Pr/Qr)/(deg+eps)
    {
        const float inv = 1.f / ((float)dg + EPS);
        float2 hs = *(const float2*)(HB + ((size_t)(unsigned)node << 9) + laneoff);
        float pre = ptd + hs.x + SP * inv;
        float a   = fmaxf(pre, 0.2f * pre);
        float t   = a * vec;
        t += __shfl_xor(t, 1);
        t += __shfl_xor(t, 2);
        t += __shfl_xor(t, 4);
        float av = __expf(t);
        S += av;
        O = fmaf(av, hs.y + SQ * inv, O);
    }

    out[(size_t)node * 64 + lane] = O / (S + EPS);
}

// ---------------------------------------------------------------------------
extern "C" void kernel_launch(void* const* d_in, const int* in_sizes, int n_in,
                              void* d_out, int out_size, void* d_ws, size_t ws_size,
                              hipStream_t stream)
{
    const float* emb_ent  = (const float*)d_in[0];
    const float* emb_rel  = (const float*)d_in[1];
    const float* attn_W   = (const float*)d_in[2];   // [64 x 192]
    const float* attn_b   = (const float*)d_in[3];
    const float* attn_vec = (const float*)d_in[4];   // 64
    const float* aggr_W   = (const float*)d_in[5];   // [64 x 128]
    const float* aggr_b   = (const float*)d_in[6];
    const int*   head     = (const int*)d_in[7];
    const int*   tail     = (const int*)d_in[8];
    const int*   rel      = (const int*)d_in[9];

    const int N = in_sizes[0] / 64;
    const int R = in_sizes[1] / 64;
    const int E = in_sizes[7];

    char* w = (char*)d_ws;
    float*  Pt  = (float*)w;          w += (size_t)N * 64 * sizeof(float);
    float2* PQh = (float2*)w;         w += (size_t)N * 64 * sizeof(float2);
    float2* PQr = (float2*)w;         w += (size_t)R * 64 * sizeof(float2);
    int* deg    = (int*)w;            w += (size_t)N * sizeof(int);
    int* incl   = (int*)w;            w += (size_t)N * sizeof(int);
    int* offs   = (int*)w;            w += (size_t)N * sizeof(int);
    int* cursor = (int*)w;            w += (size_t)N * sizeof(int);
    int* bsums  = (int*)w;            w += 256 * sizeof(int);
    unsigned int* shr = (unsigned int*)w;  w += (size_t)E * sizeof(unsigned int);

    // CSR by tail
    hipMemsetAsync(deg, 0, (size_t)N * sizeof(int), stream);
    hist_kernel<<<(E + 255) / 256, 256, 0, stream>>>(tail, E, deg);
    int nb = (N + 255) / 256;
    scan_chunk<<<nb, 256, 0, stream>>>(deg, N, incl, bsums);
    scan_tops<<<1, 256, 0, stream>>>(bsums, nb);
    scan_final<<<nb, 256, 0, stream>>>(deg, incl, bsums, N, offs, cursor);
    place_kernel<<<(E + 255) / 256, 256, 0, stream>>>(head, tail, rel, E, cursor, shr);

    // projection tables (broadcast-weights GEMMs)
    gemm_ent<<<(N + 255) / 256, 256, 0, stream>>>(emb_ent, N, attn_W, aggr_W,
                                                  attn_b, aggr_b, Pt, (float*)PQh);
    gemm_rel<<<(R + 63) / 64, 256, 0, stream>>>(emb_rel, R, attn_W, aggr_W,
                                                (float*)PQr);

    // per-node aggregation
    ingram_main<<<(N + 3) / 4, 256, 0, stream>>>(Pt, PQh, PQr, deg, offs, shr,
                                                 attn_vec, (float*)d_out, N);
}

// Round 5
// 236.805 us; speedup vs baseline: 4.5478x; 1.0821x over previous
//
#include <hip/hip_runtime.h>
#include <math.h>

#define EPS 1e-6f

__device__ __forceinline__ float4 f4fma(float s, float4 w, float4 acc) {
    acc.x = fmaf(s, w.x, acc.x);
    acc.y = fmaf(s, w.y, acc.y);
    acc.z = fmaf(s, w.z, acc.z);
    acc.w = fmaf(s, w.w, acc.w);
    return acc;
}

// bf16 round-to-nearest-even, returned in low 16 bits of a uint.
__device__ __forceinline__ unsigned f2bf(float x) {
    unsigned u = __float_as_uint(x);
    return (u + 0x7FFFu + ((u >> 16) & 1u)) >> 16;
}

// 4-column dot: out[c..c+3] = sum_k a[k] * Ws[k][cb..cb+3]; 4-way split acc.
// Ws reads are wave-uniform -> conflict-free LDS broadcast.
template <int LDW>
__device__ __forceinline__ float4 dot4cols(const float (*Ws)[LDW],
                                           const float4* a4, int cb)
{
    float4 z = make_float4(0.f, 0.f, 0.f, 0.f);
    float4 acc0 = z, acc1 = z, acc2 = z, acc3 = z;
#pragma unroll
    for (int k4 = 0; k4 < 16; ++k4) {
        float4 av = a4[k4];
        float4 w0 = *reinterpret_cast<const float4*>(&Ws[4 * k4 + 0][cb]);
        float4 w1 = *reinterpret_cast<const float4*>(&Ws[4 * k4 + 1][cb]);
        float4 w2 = *reinterpret_cast<const float4*>(&Ws[4 * k4 + 2][cb]);
        float4 w3 = *reinterpret_cast<const float4*>(&Ws[4 * k4 + 3][cb]);
        acc0 = f4fma(av.x, w0, acc0);
        acc1 = f4fma(av.y, w1, acc1);
        acc2 = f4fma(av.z, w2, acc2);
        acc3 = f4fma(av.w, w3, acc3);
    }
    return make_float4((acc0.x + acc1.x) + (acc2.x + acc3.x),
                       (acc0.y + acc1.y) + (acc2.y + acc3.y),
                       (acc0.z + acc1.z) + (acc2.z + acc3.z),
                       (acc0.w + acc1.w) + (acc2.w + acc3.w));
}

// ---------------------------------------------------------------------------
// Entity tables: one thread per row; W' (192 cols x 64 k) transposed in LDS.
//   Pt  (fp32)       = A . attn_W[:,0:64]^T
//   PQh (packed bf16)= { A.attn_W[:,64:128]^T + attn_b  (lo16),
//                        A.aggr_W[:,0:64]^T   + aggr_b  (hi16) }
// ---------------------------------------------------------------------------
__global__ __launch_bounds__(256) void gemm_ent(
    const float* __restrict__ A, int M,
    const float* __restrict__ attn_W,   // [64 x 192]
    const float* __restrict__ aggr_W,   // [64 x 128]
    const float* __restrict__ attn_b, const float* __restrict__ aggr_b,
    float* __restrict__ Pt, unsigned* __restrict__ PQh)
{
    __shared__ alignas(16) float Ws[64][196];
    const int tid = threadIdx.x;

    for (int idx = tid; idx < 64 * 192; idx += 256) {
        int c = idx >> 6, k = idx & 63;
        float v;
        if (c < 64)       v = attn_W[c * 192 + k];
        else if (c < 128) v = attn_W[(c - 64) * 192 + 64 + k];
        else              v = aggr_W[(c - 128) * 128 + k];
        Ws[k][c] = v;
    }
    __syncthreads();

    const int r = blockIdx.x * 256 + tid;
    if (r >= M) return;

    float4 a4[16];
#pragma unroll
    for (int i = 0; i < 16; ++i)
        a4[i] = *reinterpret_cast<const float4*>(A + (size_t)r * 64 + i * 4);

    for (int cg = 0; cg < 16; ++cg) {
        float4 pt = dot4cols<196>(Ws, a4, cg * 4);
        *reinterpret_cast<float4*>(Pt + (size_t)r * 64 + cg * 4) = pt;

        float4 ph = dot4cols<196>(Ws, a4, 64 + cg * 4);
        float4 qh = dot4cols<196>(Ws, a4, 128 + cg * 4);
        float4 ba = *reinterpret_cast<const float4*>(attn_b + cg * 4);
        float4 bg = *reinterpret_cast<const float4*>(aggr_b + cg * 4);
        uint4 pk;
        pk.x = f2bf(ph.x + ba.x) | (f2bf(qh.x + bg.x) << 16);
        pk.y = f2bf(ph.y + ba.y) | (f2bf(qh.y + bg.y) << 16);
        pk.z = f2bf(ph.z + ba.z) | (f2bf(qh.z + bg.z) << 16);
        pk.w = f2bf(ph.w + ba.w) | (f2bf(qh.w + bg.w) << 16);
        *reinterpret_cast<uint4*>(PQh + (size_t)r * 64 + cg * 4) = pk;
    }
}

// ---------------------------------------------------------------------------
// Relation tables (fp32, L2-resident): PQr = { A.attn_W[:,128:192]^T,
//                                              A.aggr_W[:, 64:128]^T } float2
// ---------------------------------------------------------------------------
__global__ __launch_bounds__(256) void gemm_rel(
    const float* __restrict__ A, int Mr,
    const float* __restrict__ attn_W,
    const float* __restrict__ aggr_W,
    float* __restrict__ PQr)
{
    __shared__ alignas(16) float Ws[64][132];
    const int tid = threadIdx.x;

    for (int idx = tid; idx < 64 * 128; idx += 256) {
        int c = idx >> 6, k = idx & 63;
        float v = (c < 64) ? attn_W[c * 192 + 128 + k]
                           : aggr_W[(c - 64) * 128 + 64 + k];
        Ws[k][c] = v;
    }
    __syncthreads();

    const int r = blockIdx.x * 64 + (tid & 63);
    const int q = tid >> 6;                 // col quarter 0..3
    if (r >= Mr) return;

    float4 a4[16];
#pragma unroll
    for (int i = 0; i < 16; ++i)
        a4[i] = *reinterpret_cast<const float4*>(A + (size_t)r * 64 + i * 4);

    for (int cg = 0; cg < 8; ++cg) {
        int cb = q * 32 + cg * 4;
        float4 s = dot4cols<132>(Ws, a4, cb);
#pragma unroll
        for (int i = 0; i < 4; ++i) {
            int c = cb + i;
            float v = (i == 0) ? s.x : (i == 1) ? s.y : (i == 2) ? s.z : s.w;
            if (c < 64) PQr[((size_t)r * 64 + c) * 2]            = v;
            else        PQr[((size_t)r * 64 + (c - 64)) * 2 + 1] = v;
        }
    }
}

// ---------------------------------------------------------------------------
// CSR build: histogram, scan, placement
// ---------------------------------------------------------------------------
__global__ __launch_bounds__(256) void hist_kernel(const int* __restrict__ tail, int E,
                                                   int* __restrict__ deg)
{
    int e = blockIdx.x * 256 + threadIdx.x;
    if (e < E) atomicAdd(&deg[tail[e]], 1);
}

__global__ __launch_bounds__(256) void scan_chunk(const int* __restrict__ deg, int n,
                                                  int* __restrict__ incl, int* __restrict__ bsums)
{
    __shared__ int s[256];
    int tid = threadIdx.x;
    int i = blockIdx.x * 256 + tid;
    int v = (i < n) ? deg[i] : 0;
    int acc = v;
    s[tid] = acc;
    __syncthreads();
#pragma unroll
    for (int off = 1; off < 256; off <<= 1) {
        int add = (tid >= off) ? s[tid - off] : 0;
        __syncthreads();
        acc += add;
        s[tid] = acc;
        __syncthreads();
    }
    if (i < n) incl[i] = acc;
    if (tid == 255) bsums[blockIdx.x] = acc;
}

__global__ __launch_bounds__(256) void scan_tops(int* __restrict__ bsums, int nb)
{
    __shared__ int s[256];
    int tid = threadIdx.x;
    int v = (tid < nb) ? bsums[tid] : 0;
    int acc = v;
    s[tid] = acc;
    __syncthreads();
#pragma unroll
    for (int off = 1; off < 256; off <<= 1) {
        int add = (tid >= off) ? s[tid - off] : 0;
        __syncthreads();
        acc += add;
        s[tid] = acc;
        __syncthreads();
    }
    if (tid < nb) bsums[tid] = acc - v;
}

__global__ __launch_bounds__(256) void scan_final(const int* __restrict__ deg,
                                                  const int* __restrict__ incl,
                                                  const int* __restrict__ bsums, int n,
                                                  int* __restrict__ off, int* __restrict__ cursor)
{
    int i = blockIdx.x * 256 + threadIdx.x;
    if (i < n) {
        int e = incl[i] - deg[i] + bsums[blockIdx.x];
        off[i] = e;
        cursor[i] = e;
    }
}

__global__ __launch_bounds__(256) void place_kernel(const int* __restrict__ head,
                                                    const int* __restrict__ tail,
                                                    const int* __restrict__ rel, int E,
                                                    int* __restrict__ cursor,
                                                    unsigned int* __restrict__ shr)
{
    int e = blockIdx.x * 256 + threadIdx.x;
    if (e < E) {
        int t = tail[e];
        int p = atomicAdd(&cursor[t], 1);
        shr[p] = ((unsigned int)head[e] << 8) | (unsigned int)rel[e];
    }
}

// ---------------------------------------------------------------------------
// Main: one wave per node, lane = output dim. Edge metadata through SGPRs
// (readfirstlane -> s_load + SALU unpack). PQh is bf16-packed: row stride
// 256B, so (p & ~255) IS the byte offset of head row. No-max softmax.
// ---------------------------------------------------------------------------
__global__ __launch_bounds__(256) void ingram_main(
    const float* __restrict__ Pt,
    const unsigned* __restrict__ PQh,    // packed {bf16 Ph+attn_b | bf16 Qh+aggr_b}
    const float2* __restrict__ PQr,      // {Pr, Qr} fp32
    const int* __restrict__ deg, const int* __restrict__ off,
    const unsigned* __restrict__ shr,
    const float* __restrict__ attn_vec,
    float* __restrict__ out, int N)
{
    const int lane = threadIdx.x & 63;
    const int node = blockIdx.x * 4 + (threadIdx.x >> 6);
    if (node >= N) return;

    const float vec = attn_vec[lane];
    const float ptd = Pt[(size_t)node * 64 + lane];
    const char* HBc = (const char*)PQh;
    const char* RBc = (const char*)PQr;
    const unsigned loff4 = (unsigned)lane << 2;
    const unsigned loff8 = (unsigned)lane << 3;

    const int start = __builtin_amdgcn_readfirstlane(off[node]);
    const int dg    = __builtin_amdgcn_readfirstlane(deg[node]);

    float S = 0.f, O = 0.f, SP = 0.f, SQ = 0.f;

#pragma unroll 8
    for (int j = 0; j < dg; ++j) {
        unsigned p = (unsigned)__builtin_amdgcn_readfirstlane((int)shr[start + j]);
        unsigned hb = *(const unsigned*)(HBc + (p & 0xFFFFFF00u) + loff4);
        float2 rc   = *(const float2*)(RBc + ((p & 255u) << 9) + loff8);
        float hx = __uint_as_float(hb << 16);           // Ph + attn_b
        float hy = __uint_as_float(hb & 0xFFFF0000u);   // Qh + aggr_b
        SP += rc.x;
        SQ += rc.y;
        float pre = ptd + hx + rc.x;
        float a   = fmaxf(pre, 0.2f * pre);             // leaky_relu(0.2)
        float t   = a * vec;
        t += __shfl_xor(t, 1);
        t += __shfl_xor(t, 2);
        t += __shfl_xor(t, 4);
        float av = __expf(t);
        S += av;
        O = fmaf(av, hy + rc.y, O);
    }

    // self-loop: rel features = (sum of incoming Pr/Qr)/(deg+eps)
    {
        const float inv = 1.f / ((float)dg + EPS);
        unsigned hb = *(const unsigned*)(HBc + ((unsigned)node << 8) + loff4);
        float hx = __uint_as_float(hb << 16);
        float hy = __uint_as_float(hb & 0xFFFF0000u);
        float pre = ptd + hx + SP * inv;
        float a   = fmaxf(pre, 0.2f * pre);
        float t   = a * vec;
        t += __shfl_xor(t, 1);
        t += __shfl_xor(t, 2);
        t += __shfl_xor(t, 4);
        float av = __expf(t);
        S += av;
        O = fmaf(av, hy + SQ * inv, O);
    }

    out[(size_t)node * 64 + lane] = O / (S + EPS);
}

// ---------------------------------------------------------------------------
extern "C" void kernel_launch(void* const* d_in, const int* in_sizes, int n_in,
                              void* d_out, int out_size, void* d_ws, size_t ws_size,
                              hipStream_t stream)
{
    const float* emb_ent  = (const float*)d_in[0];
    const float* emb_rel  = (const float*)d_in[1];
    const float* attn_W   = (const float*)d_in[2];   // [64 x 192]
    const float* attn_b   = (const float*)d_in[3];
    const float* attn_vec = (const float*)d_in[4];   // 64
    const float* aggr_W   = (const float*)d_in[5];   // [64 x 128]
    const float* aggr_b   = (const float*)d_in[6];
    const int*   head     = (const int*)d_in[7];
    const int*   tail     = (const int*)d_in[8];
    const int*   rel      = (const int*)d_in[9];

    const int N = in_sizes[0] / 64;
    const int R = in_sizes[1] / 64;
    const int E = in_sizes[7];

    char* w = (char*)d_ws;
    float*    Pt  = (float*)w;        w += (size_t)N * 64 * sizeof(float);
    unsigned* PQh = (unsigned*)w;     w += (size_t)N * 64 * sizeof(unsigned);
    float2*   PQr = (float2*)w;       w += (size_t)R * 64 * sizeof(float2);
    int* deg    = (int*)w;            w += (size_t)N * sizeof(int);
    int* incl   = (int*)w;            w += (size_t)N * sizeof(int);
    int* offs   = (int*)w;            w += (size_t)N * sizeof(int);
    int* cursor = (int*)w;            w += (size_t)N * sizeof(int);
    int* bsums  = (int*)w;            w += 256 * sizeof(int);
    unsigned int* shr = (unsigned int*)w;  w += (size_t)E * sizeof(unsigned int);

    // CSR by tail
    hipMemsetAsync(deg, 0, (size_t)N * sizeof(int), stream);
    hist_kernel<<<(E + 255) / 256, 256, 0, stream>>>(tail, E, deg);
    int nb = (N + 255) / 256;
    scan_chunk<<<nb, 256, 0, stream>>>(deg, N, incl, bsums);
    scan_tops<<<1, 256, 0, stream>>>(bsums, nb);
    scan_final<<<nb, 256, 0, stream>>>(deg, incl, bsums, N, offs, cursor);
    place_kernel<<<(E + 255) / 256, 256, 0, stream>>>(head, tail, rel, E, cursor, shr);

    // projection tables
    gemm_ent<<<(N + 255) / 256, 256, 0, stream>>>(emb_ent, N, attn_W, aggr_W,
                                                  attn_b, aggr_b, Pt, PQh);
    gemm_rel<<<(R + 63) / 64, 256, 0, stream>>>(emb_rel, R, attn_W, aggr_W,
                                                (float*)PQr);

    // per-node aggregation
    ingram_main<<<(N + 3) / 4, 256, 0, stream>>>(Pt, PQh, PQr, deg, offs, shr,
                                                 attn_vec, (float*)d_out, N);
}